// Round 8
// baseline (343306.177 us; speedup 1.0000x reference)
//
#include <hip/hip_runtime.h>
#include <math.h>

#define T_STEPS 22550
#define NWG 32
#define NTHR 256

typedef unsigned long long ull;

// ---- u64 slot indices ----
#define SL_H1   0          // [32][8]   h1 lower-half elems
#define SL_O1   256        // [32][16]  o1 rows
#define SL_AM1  768        // [32]      per-WG c-logit max
#define SL_H2   800        // [32][16]  h2 elems
#define SL_O3   1312       // [32][16]  o3 rows
#define SL_AM2  1824       // [2][32]   per-WG f-logit max, parity banks
#define SL_END  1888

// ---- float offsets in ws ----
#define OF_SLOT  64
#define OF_AFTER (OF_SLOT + SL_END*2)
#define OF_BUFA  OF_AFTER                 // conv stage0 out [128][412]
#define OF_BUFB  (OF_BUFA + 128*412)      // conv stage1 out [128][2052]
#define OF_COND  (OF_BUFB + 128*2052)     // cond [T][128]

__global__ void k_init(float* ws){
  int i = blockIdx.x*blockDim.x + threadIdx.x;
  ull* sl = (ull*)(ws + OF_SLOT);
  if (i < SL_END) __hip_atomic_store(&sl[i], 0ULL, __ATOMIC_RELAXED, __HIP_MEMORY_SCOPE_AGENT);
}

// transposed conv (lhs_dilation=sc), padding e, then relu.
// mode 0: y[c][j]; mode 1: write cond[t=j-1][c] (crop [1:-1], transpose)
__global__ void k_upconv(const float* __restrict__ x, int instride, int inoff,
                         const float* __restrict__ w, const float* __restrict__ b,
                         float* __restrict__ y, int Cin, int Lin, int K, int sc, int e,
                         int Lout, int mode)
{
  int j = blockIdx.x*blockDim.x + threadIdx.x;
  int c = blockIdx.y;
  if (j >= Lout) return;
  float acc = b[c];
  int kstart = ((e - j) % sc + sc) % sc;
  for (int i = 0; i < Cin; ++i){
    const float* wci = w + (c*Cin + i)*K;
    const float* xi  = x + i*instride + inoff;
    for (int k = kstart; k < K; k += sc){
      int qd = j - e + k;
      if (qd >= 0){
        int qq = qd / sc;
        if (qq < Lin) acc += wci[k]*xi[qq];
      }
    }
  }
  acc = fmaxf(acc, 0.f);
  if (mode == 0) y[c*Lout + j] = acc;
  else { int t = j - 1; if (t >= 0 && t < T_STEPS) y[t*128 + c] = acc; }
}

__device__ __forceinline__ float sigm(float x){ return 1.f/(1.f + expf(-x)); }

// publish = fire-and-forget atomic RMW: forced prompt arrival at coherence point
__device__ __forceinline__ void pub64(ull* p, ull pk){
  (void)__hip_atomic_exchange(p, pk, __ATOMIC_RELAXED, __HIP_MEMORY_SCOPE_AGENT);
}
__device__ __forceinline__ ull ld64(ull* p){
  return __hip_atomic_load(p, __ATOMIC_RELAXED, __HIP_MEMORY_SCOPE_AGENT);
}
__device__ __forceinline__ float spin_data(ull* p, unsigned tag){
  ull pk = ld64(p);
  while ((unsigned)pk != tag) pk = ld64(p);
  return __uint_as_float((unsigned)(pk >> 32));
}
__device__ __forceinline__ ull spin_am(ull* p, unsigned tag){
  ull pk = ld64(p);
  while ((unsigned)(pk & 0xFFFFFFu) != tag) pk = ld64(p);
  return pk;
}
__device__ __forceinline__ ull pack_data(float v, unsigned tag){
  return ((ull)__float_as_uint(v) << 32) | (ull)tag;
}

__launch_bounds__(NTHR)
__global__ void k_wavernn(const float* __restrict__ Wx, const float* __restrict__ bx,
                          const float* __restrict__ Wh, const float* __restrict__ bh,
                          const float* __restrict__ O1w, const float* __restrict__ O1b,
                          const float* __restrict__ O2w, const float* __restrict__ O2b,
                          const float* __restrict__ O3w, const float* __restrict__ O3b,
                          const float* __restrict__ O4w, const float* __restrict__ O4b,
                          float* ws, float* __restrict__ out)
{
  __shared__ __align__(16) float h_s[512];
  __shared__ __align__(16) float m_s[128];
  __shared__ __align__(16) float h1c_s[256];
  __shared__ __align__(16) float o_s[512];
  __shared__ float hg_s[48], xgb_s[48], xg1_s[48];
  __shared__ float red_s[8], sc_s[8];
  __shared__ float wc0_s[48], wc1_s[48], wc2_s[48], bx_s[48], bh_s[48];

  const int tid = threadIdx.x, g = blockIdx.x;
  ull* sl = (ull*)(ws + OF_SLOT);
  const float* cond = ws + OF_COND;
  float* out_samp = out;
  float* out_log  = out + T_STEPS;

  // ---- preloads (ownership: WG g owns h elems {g+32i}; gate rows {gate*512+elem}) ----
  if (tid < 48){
    int row = (tid>>4)*512 + g + 32*(tid&15);
    wc0_s[tid] = Wx[(size_t)row*131 + 0];
    wc1_s[tid] = Wx[(size_t)row*131 + 1];
    wc2_s[tid] = Wx[(size_t)row*131 + 2];
    bx_s[tid]  = bx[row];
    bh_s[tid]  = bh[row];
  }
  // O1/O3: 16 rows/WG {g+32*m16}, 16 lanes/row, 16 contiguous cols/lane
  const int m16 = tid>>4, c16 = tid&15;
  const int rowO1 = g + 32*m16;
  float wO1r[16], wO3r[16];
  #pragma unroll
  for (int k=0;k<16;++k){
    wO1r[k] = O1w[(size_t)rowO1*256 + c16*16 + k];
    wO3r[k] = O3w[(size_t)rowO1*256 + c16*16 + k];
  }
  const float bO1r = O1b[rowO1], bO3r = O3b[rowO1];
  // O2/O4: 8 rows/WG {g+32*m8}, 32 lanes/row, stride-32 cols
  const int m8 = tid>>5, l32 = tid&31;
  const int row2 = g + 32*m8;
  float wO2r[16], wO4r[16];
  #pragma unroll
  for (int k=0;k<16;++k){
    wO2r[k] = O2w[(size_t)row2*512 + l32 + 32*k];
    wO4r[k] = O4w[(size_t)row2*512 + l32 + 32*k];
  }
  const float bO2 = O2b[row2], bO4 = O4b[row2];

  h_s[tid] = 0.f; h_s[tid+256] = 0.f;
  if (tid < 128) m_s[tid] = cond[tid];
  if (tid == 0){ sc_s[0] = 0.f; sc_s[1] = 0.f; }
  __syncthreads();

  // xgb = Wx[:,3:]@m + bx    (48 rows x 4 lanes; reads m_s)
  #define COMPUTE_WX() do { \
    if (tid < 192){ \
      const int li_ = tid>>2, q_ = tid&3; \
      const int row_ = (li_>>4)*512 + g + 32*(li_&15); \
      const float* WxR = Wx + (size_t)row_*131 + 3; \
      float aX = 0.f; \
      _Pragma("unroll") \
      for (int kk=0; kk<32; ++kk){ \
        int f_ = q_*32 + ((kk + 8*q_) & 31); \
        aX += WxR[f_]*m_s[f_]; \
      } \
      aX += __shfl_xor(aX,1); aX += __shfl_xor(aX,2); \
      if (q_ == 0) xgb_s[li_] = aX + bx_s[li_]; \
    } } while(0)

  // hg = Wh@h + bh           (48 rows x 4 lanes, bank-swizzled LDS reads of h_s)
  #define COMPUTE_WH() do { \
    if (tid < 192){ \
      const int li_ = tid>>2, q_ = tid&3; \
      const int row_ = (li_>>4)*512 + g + 32*(li_&15); \
      const float4* W4 = (const float4*)(Wh + (size_t)row_*512); \
      const float4* H4 = (const float4*)h_s; \
      float aH = 0.f; \
      _Pragma("unroll") \
      for (int kk=0; kk<32; ++kk){ \
        int f_ = q_*32 + ((kk + 2*q_) & 31); \
        float4 w = W4[f_], v = H4[f_]; \
        aH += w.x*v.x + w.y*v.y + w.z*v.z + w.w*v.w; \
      } \
      aH += __shfl_xor(aH,1); aH += __shfl_xor(aH,2); \
      if (q_ == 0) hg_s[li_] = aH + bh_s[li_]; \
    } } while(0)

  COMPUTE_WX();
  COMPUTE_WH();

  for (int t = 0; t < T_STEPS; ++t){
    const unsigned tag = (unsigned)(t + 1);
    __syncthreads();                        // hg/xgb/sc_s ready

    // (a) xg1 = xgb + c*w0 + f*w1 ; early-load next cond row (consumed by WX mid-step)
    if (tid < 48) xg1_s[tid] = xgb_s[tid] + sc_s[0]*wc0_s[tid] + sc_s[1]*wc1_s[tid];
    if (tid < 128 && t + 1 < T_STEPS) m_s[tid] = cond[(size_t)(t+1)*128 + tid];
    __syncthreads();

    // (b) GRU1 gates for own lower-8 elems, publish h1
    if (tid < 8){
      float r = sigm(xg1_s[tid]     + hg_s[tid]);
      float z = sigm(xg1_s[16+tid]  + hg_s[16+tid]);
      float n = tanhf(xg1_s[32+tid] + r*hg_s[32+tid]);
      float h1 = (1.f - z)*n + z*h_s[g + 32*tid];
      pub64(&sl[SL_H1 + g*8 + tid], pack_data(h1, tag));
    }
    // (c) gather full h1[0:256]
    h1c_s[tid] = spin_data(&sl[SL_H1 + (tid & 31)*8 + (tid >> 5)], tag);
    __syncthreads();

    // (d) o1: own 16 rows, publish from reducing lane
    {
      float acc = 0.f;
      #pragma unroll
      for (int k=0;k<16;++k) acc += wO1r[k]*h1c_s[c16*16 + k];
      acc += __shfl_xor(acc,1); acc += __shfl_xor(acc,2);
      acc += __shfl_xor(acc,4); acc += __shfl_xor(acc,8);
      if (c16 == 0) pub64(&sl[SL_O1 + g*16 + m16], pack_data(fmaxf(acc + bO1r, 0.f), tag));
    }
    // (e) gather o1
    o_s[tid]       = spin_data(&sl[SL_O1 + (tid & 31)*16 + (tid >> 5)], tag);
    o_s[tid + 256] = spin_data(&sl[SL_O1 + (tid & 31)*16 + (tid >> 5) + 8], tag);
    __syncthreads();

    // (f) O2 own 8 rows -> red_s; tid0 reduces + publishes am1
    {
      float acc = 0.f;
      #pragma unroll
      for (int k=0;k<16;++k) acc += wO2r[k]*o_s[l32 + 32*k];
      acc += __shfl_xor(acc,1); acc += __shfl_xor(acc,2); acc += __shfl_xor(acc,4);
      acc += __shfl_xor(acc,8); acc += __shfl_xor(acc,16);
      if (l32 == 0){ float v = acc + bO2; out_log[(size_t)t*512 + row2] = v; red_s[m8] = v; }
    }
    __syncthreads();
    if (tid == 0){
      float bv = red_s[0]; int bi = g;          // rows ascend with m -> strict > = first max
      #pragma unroll
      for (int m=1;m<8;++m){ float v = red_s[m]; if (v > bv){ bv = v; bi = g + 32*m; } }
      pub64(&sl[SL_AM1 + g],
            ((ull)__float_as_uint(bv) << 32) | ((ull)(unsigned)bi << 24) | tag);
    }

    // next step's xgb (independent of c/f) — hides the am1 trip
    COMPUTE_WX();

    // (g) gather am1, global argmax -> c
    if (tid < 32){
      ull pk = spin_am(&sl[SL_AM1 + tid], tag);
      float bv = __uint_as_float((unsigned)(pk >> 32));
      int   bi = (int)((pk >> 24) & 0xFFu);
      #pragma unroll
      for (int off=16; off>=1; off>>=1){
        float ov = __shfl_xor(bv,off); int oi = __shfl_xor(bi,off);
        if (ov > bv || (ov == bv && oi < bi)){ bv = ov; bi = oi; }
      }
      if (tid == 0){ sc_s[2] = (float)bi; sc_s[3] = (float)bi/127.5f - 1.f; }
    }
    __syncthreads();

    // (h) GRU2 for all 16 own elems, publish h2
    if (tid < 16){
      float cn = sc_s[3];
      float r = sigm(xg1_s[tid]     + cn*wc2_s[tid]     + hg_s[tid]);
      float z = sigm(xg1_s[16+tid]  + cn*wc2_s[16+tid]  + hg_s[16+tid]);
      float n = tanhf(xg1_s[32+tid] + cn*wc2_s[32+tid]  + r*hg_s[32+tid]);
      float h2 = (1.f - z)*n + z*h_s[g + 32*tid];
      pub64(&sl[SL_H2 + g*16 + tid], pack_data(h2, tag));
    }
    __syncthreads();                        // old-h reads done before h_s overwrite
    // (i) gather h2 into h_s
    h_s[tid]       = spin_data(&sl[SL_H2 + (tid & 31)*16 + (tid >> 5)], tag);
    h_s[tid + 256] = spin_data(&sl[SL_H2 + (tid & 31)*16 + (tid >> 5) + 8], tag);
    __syncthreads();

    // (j) o3: own 16 rows from h2 upper half, publish
    {
      float acc = 0.f;
      #pragma unroll
      for (int k=0;k<16;++k) acc += wO3r[k]*h_s[256 + c16*16 + k];
      acc += __shfl_xor(acc,1); acc += __shfl_xor(acc,2);
      acc += __shfl_xor(acc,4); acc += __shfl_xor(acc,8);
      if (c16 == 0) pub64(&sl[SL_O3 + g*16 + m16], pack_data(fmaxf(acc + bO3r, 0.f), tag));
    }
    // (k) gather o3
    o_s[tid]       = spin_data(&sl[SL_O3 + (tid & 31)*16 + (tid >> 5)], tag);
    o_s[tid + 256] = spin_data(&sl[SL_O3 + (tid & 31)*16 + (tid >> 5) + 8], tag);
    __syncthreads();

    // (l) O4 own 8 rows -> red_s; tid0 publishes am2 (parity bank)
    {
      float acc = 0.f;
      #pragma unroll
      for (int k=0;k<16;++k) acc += wO4r[k]*o_s[l32 + 32*k];
      acc += __shfl_xor(acc,1); acc += __shfl_xor(acc,2); acc += __shfl_xor(acc,4);
      acc += __shfl_xor(acc,8); acc += __shfl_xor(acc,16);
      if (l32 == 0){ float v = acc + bO4; out_log[(size_t)t*512 + 256 + row2] = v; red_s[m8] = v; }
    }
    __syncthreads();
    if (tid == 0){
      float bv = red_s[0]; int bi = g;
      #pragma unroll
      for (int m=1;m<8;++m){ float v = red_s[m]; if (v > bv){ bv = v; bi = g + 32*m; } }
      pub64(&sl[SL_AM2 + (t & 1)*32 + g],
            ((ull)__float_as_uint(bv) << 32) | ((ull)(unsigned)bi << 24) | tag);
    }

    // next step's hg (needs h_s = h2, already gathered) — hides the am2 trip
    COMPUTE_WH();

    // (n) gather am2 -> f, carries, sample
    if (tid < 32){
      ull pk = spin_am(&sl[SL_AM2 + (t & 1)*32 + tid], tag);
      float bv = __uint_as_float((unsigned)(pk >> 32));
      int   bi = (int)((pk >> 24) & 0xFFu);
      #pragma unroll
      for (int off=16; off>=1; off>>=1){
        float ov = __shfl_xor(bv,off); int oi = __shfl_xor(bi,off);
        if (ov > bv || (ov == bv && oi < bi)){ bv = ov; bi = oi; }
      }
      if (tid == 0){
        sc_s[0] = sc_s[3];                       // c carry
        sc_s[1] = (float)bi/127.5f - 1.f;        // f carry
        if (g == 0) out_samp[t] = (sc_s[2]*256.f + (float)bi)/32767.5f - 1.f;
      }
    }
    // loop-top __syncthreads() publishes hg/xgb/sc
  }
}

extern "C" void kernel_launch(void* const* d_in, const int* in_sizes, int n_in,
                              void* d_out, int out_size, void* d_ws, size_t ws_size,
                              hipStream_t stream)
{
  const float* mels  = (const float*)d_in[0];
  const float* up_w0 = (const float*)d_in[1]; const float* up_b0 = (const float*)d_in[2];
  const float* up_w1 = (const float*)d_in[3]; const float* up_b1 = (const float*)d_in[4];
  const float* up_w2 = (const float*)d_in[5]; const float* up_b2 = (const float*)d_in[6];
  const float* Wx  = (const float*)d_in[7];  const float* bx  = (const float*)d_in[8];
  const float* Wh  = (const float*)d_in[9];  const float* bh  = (const float*)d_in[10];
  const float* O1w = (const float*)d_in[11]; const float* O1b = (const float*)d_in[12];
  const float* O2w = (const float*)d_in[13]; const float* O2b = (const float*)d_in[14];
  const float* O3w = (const float*)d_in[15]; const float* O3b = (const float*)d_in[16];
  const float* O4w = (const float*)d_in[17]; const float* O4b = (const float*)d_in[18];
  float* ws  = (float*)d_ws;
  float* out = (float*)d_out;

  k_init<<<8, 256, 0, stream>>>(ws);

  // upsample: 84 -> 412 -> 2052 -> 22552 (crop [1:-1] -> cond[22550][128])
  k_upconv<<<dim3((412  +127)/128, 128), 128, 0, stream>>>(mels,        86,   1, up_w0, up_b0,
            ws+OF_BUFA,  80,   84, 11,  5, 3,   412, 0);
  k_upconv<<<dim3((2052 +127)/128, 128), 128, 0, stream>>>(ws+OF_BUFA, 412,   0, up_w1, up_b1,
            ws+OF_BUFB, 128,  412, 11,  5, 3,  2052, 0);
  k_upconv<<<dim3((22552+127)/128, 128), 128, 0, stream>>>(ws+OF_BUFB, 2052,  0, up_w2, up_b2,
            ws+OF_COND, 128, 2052, 23, 11, 6, 22552, 1);

  k_wavernn<<<NWG, NTHR, 0, stream>>>(Wx, bx, Wh, bh, O1w, O1b, O2w, O2b,
                                      O3w, O3b, O4w, O4b, ws, out);
}